// Round 5
// baseline (270.807 us; speedup 1.0000x reference)
//
#include <hip/hip_runtime.h>

// ---------------------------------------------------------------------------
// RoBERTa self-attention: QKV projection (bf16 MFMA) + flash attention.
// B=4, S=2048, D=1024, H=16, HD=64.  fp32 in/out, bf16 internal, fp32 acc.
// R4: R3's 32x32x16 attn, but P-repack cross-lane exchange via
//     __shfl_xor(32)+select instead of inline-asm v_permlane32_swap
//     (prime suspect for R3's 1.1e-2 absmax: unverified swap semantics).
// ---------------------------------------------------------------------------

typedef __bf16 bf16;
typedef bf16  bf16x8 __attribute__((ext_vector_type(8)));
typedef bf16  bf16x4 __attribute__((ext_vector_type(4)));
typedef float f32x4  __attribute__((ext_vector_type(4)));
typedef float f32x16 __attribute__((ext_vector_type(16)));

#define MFMA16(A, B, C) __builtin_amdgcn_mfma_f32_16x16x32_bf16((A), (B), (C), 0, 0, 0)
#define MFMA32(A, B, C) __builtin_amdgcn_mfma_f32_32x32x16_bf16((A), (B), (C), 0, 0, 0)

constexpr int BB = 4, SS = 2048, DD = 1024, HH = 16, HD = 64;
constexpr float SCALE = 0.125f;                       // 1/sqrt(64)
constexpr float LOG2E = 1.44269504088896f;
constexpr float SCALE_LOG2E = SCALE * LOG2E;

__device__ __forceinline__ float fast_exp2(float x) {
#if __has_builtin(__builtin_amdgcn_exp2f)
  return __builtin_amdgcn_exp2f(x);
#else
  return exp2f(x);
#endif
}

__device__ __forceinline__ bf16x8 cvt8(f32x4 a, f32x4 b) {
  bf16x8 r;
  r[0] = (bf16)a[0]; r[1] = (bf16)a[1]; r[2] = (bf16)a[2]; r[3] = (bf16)a[3];
  r[4] = (bf16)b[0]; r[5] = (bf16)b[1]; r[6] = (bf16)b[2]; r[7] = (bf16)b[3];
  return r;
}

__device__ __forceinline__ unsigned pack2(float lo, float hi) {
  union { bf16 h[2]; unsigned u; } r;
  r.h[0] = (bf16)lo; r.h[1] = (bf16)hi;
  return r.u;
}

// ---------------------------------------------------------------------------
// Kernel 1: Y = X @ W^T + b, output bf16.  (unchanged: ~63us, ~817 TF)
//   z==0 -> Q [8192,1024];  z==1 -> K [8192,1024];
//   z==2 -> V transposed per-head: Vt[(b*16+h)*64 + d][s]
// ---------------------------------------------------------------------------
__global__ __launch_bounds__(256, 2) void qkv_gemm(
    const float* __restrict__ X,
    const float* __restrict__ Wq, const float* __restrict__ bq,
    const float* __restrict__ Wk, const float* __restrict__ bk,
    const float* __restrict__ Wv, const float* __restrict__ bv,
    bf16* __restrict__ Qo, bf16* __restrict__ Ko, bf16* __restrict__ Vt) {
  const int z = blockIdx.z;
  const float* W    = (z == 0) ? Wq : (z == 1) ? Wk : Wv;
  const float* bias = (z == 0) ? bq : (z == 1) ? bk : bv;

  __shared__ bf16 As[128 * 64];
  __shared__ bf16 Bs[128 * 64];

  const int tid  = threadIdx.x;
  const int lane = tid & 63;
  const int w    = tid >> 6;
  const int wr   = w >> 1, wc = w & 1;
  const int m0   = blockIdx.x * 128;
  const int n0   = blockIdx.y * 128;
  const int c    = lane & 15, g = lane >> 4;

  f32x4 acc[4][4];
#pragma unroll
  for (int i = 0; i < 4; ++i)
#pragma unroll
    for (int j = 0; j < 4; ++j) acc[i][j] = f32x4{0.f, 0.f, 0.f, 0.f};

  for (int k0 = 0; k0 < DD; k0 += 64) {
    __syncthreads();
#pragma unroll
    for (int it = 0; it < 4; ++it) {
      int idx = tid + it * 256;       // chunk id (chunk = 8 bf16)
      int row = idx >> 3, c8 = idx & 7;
      const f32x4* ga = (const f32x4*)(X + (size_t)(m0 + row) * DD + k0 + c8 * 8);
      f32x4 a0 = ga[0], a1 = ga[1];
      *(bf16x8*)(&As[row * 64 + ((c8 * 8) ^ ((row & 7) << 3))]) = cvt8(a0, a1);
      const f32x4* gb = (const f32x4*)(W + (size_t)(n0 + row) * DD + k0 + c8 * 8);
      f32x4 b0 = gb[0], b1 = gb[1];
      *(bf16x8*)(&Bs[row * 64 + ((c8 * 8) ^ ((row & 7) << 3))]) = cvt8(b0, b1);
    }
    __syncthreads();

#pragma unroll
    for (int kk = 0; kk < 64; kk += 32) {
      bf16x8 af[4], bfr[4];
#pragma unroll
      for (int m = 0; m < 4; ++m) {
        int row = wr * 64 + m * 16 + c;
        af[m] = *(const bf16x8*)(&As[row * 64 + ((kk + g * 8) ^ ((row & 7) << 3))]);
      }
#pragma unroll
      for (int n = 0; n < 4; ++n) {
        int row = wc * 64 + n * 16 + c;
        bfr[n] = *(const bf16x8*)(&Bs[row * 64 + ((kk + g * 8) ^ ((row & 7) << 3))]);
      }
#pragma unroll
      for (int m = 0; m < 4; ++m)
#pragma unroll
        for (int n = 0; n < 4; ++n)
          acc[m][n] = MFMA16(af[m], bfr[n], acc[m][n]);
    }
  }

#pragma unroll
  for (int n = 0; n < 4; ++n) {
    int colg = n0 + wc * 64 + n * 16 + c;
    float bv_ = bias[colg];
#pragma unroll
    for (int m = 0; m < 4; ++m) {
      int rowg = m0 + wr * 64 + m * 16 + g * 4;
      f32x4 a = acc[m][n];
      if (z < 2) {
        bf16* dst = (z == 0) ? Qo : Ko;
#pragma unroll
        for (int j = 0; j < 4; ++j)
          dst[(size_t)(rowg + j) * DD + colg] = (bf16)(a[j] + bv_);
      } else {
        int bi = rowg >> 11, s = rowg & 2047;
        int hh = colg >> 6, dd = colg & 63;
        bf16x4 pv;
#pragma unroll
        for (int j = 0; j < 4; ++j) pv[j] = (bf16)(a[j] + bv_);
        *(bf16x4*)(&Vt[(((size_t)bi * HH + hh) * HD + dd) * SS + s]) = pv;
      }
    }
  }
}

// ---------------------------------------------------------------------------
// Kernel 2: flash attention, 32x32x16 MFMA. Grid (B*H, S/128), 4 waves.
// Wave w owns q rows [qb*128 + w*32, +32).  Per-lane: q = lane&31, hi=lane>>5.
//
// Layouts (mfma_f32_32x32x16_bf16):
//   A[row][k]: row=lane&31, k=8*hi+e ;  B[k][col]: col=lane&31, k=8*hi+e
//   C/D reg r: col=lane&31, row=(r&3)+8*(r>>2)+4*hi   [m74/m101-verified]
//
// QK^T swapped: S^T[kv][q] = mfma(A=K, B=Q^T); st reg r holds
//   kv_local = 8*(r>>2) + 4*hi + (r&3), all for q=lane&31.
// PV B-frag (slice covers 16 kv): lane (q,hi) element e=4*fh+j needs
//   st reg 4*(2*s2+hi)+j of the hi'=fh half -> 4x shfl_xor(32) + select.
// Softmax: fixed-base exp2; per-lane lsum partials, one shfl_xor(32) at end.
// K/V tiles (64 kv) LDS double-buffered, XOR-swizzled chunk^=row&7.
// ---------------------------------------------------------------------------
__global__ __launch_bounds__(256) void attn(
    const bf16* __restrict__ Q,   // [B*S, D]
    const bf16* __restrict__ K,   // [B*S, D]
    const bf16* __restrict__ Vt,  // [(b*16+h)*64 + d][S]
    const float* __restrict__ mask,  // [B, S] additive
    float* __restrict__ out) {       // [B, S, D] fp32
  __shared__ bf16 Ks[2][64 * 64];
  __shared__ bf16 Vs[2][64 * 64];

  const int bh = blockIdx.x;  // 0..63
  const int qb = blockIdx.y;  // 0..15
  const int b = bh >> 4, h = bh & 15;
  const int lane = threadIdx.x & 63;
  const int w = threadIdx.x >> 6;
  const int l31 = lane & 31, hi = lane >> 5;
  const int hi4 = hi * 4, hi8 = hi * 8;
  const int qg = qb * 128 + w * 32 + l31;  // this lane's q row

  const bf16* qptr = Q + ((size_t)(b * SS + qg)) * DD + h * HD;
  bf16x8 qB[4];
#pragma unroll
  for (int ks = 0; ks < 4; ++ks)
    qB[ks] = *(const bf16x8*)(qptr + ks * 16 + hi8);

  const bf16* Kbase = K + ((size_t)b * SS) * DD + h * HD;
  const bf16* Vbase = Vt + ((size_t)bh * HD) * SS;
  const float* mbase = mask + b * SS;

  const int srow = lane >> 3;
  const int sj   = lane & 7;
  const int r0   = w * 16 + srow, r1 = r0 + 8;
  const int swz0 = r0 * 64 + ((sj ^ (r0 & 7)) * 8);
  const int swz1 = r1 * 64 + ((sj ^ (r1 & 7)) * 8);

  f32x4 lacc = {0.f, 0.f, 0.f, 0.f};
  f32x16 acc[2] = {};

  bf16x8 stK0, stK1, stV0, stV1;

  // ---- prologue: stage tile 0 into buf 0 ----
  stK0 = *(const bf16x8*)(Kbase + (size_t)r0 * DD + sj * 8);
  stK1 = *(const bf16x8*)(Kbase + (size_t)r1 * DD + sj * 8);
  stV0 = *(const bf16x8*)(Vbase + (size_t)r0 * SS + sj * 8);
  stV1 = *(const bf16x8*)(Vbase + (size_t)r1 * SS + sj * 8);
  *(bf16x8*)(&Ks[0][swz0]) = stK0;
  *(bf16x8*)(&Ks[0][swz1]) = stK1;
  *(bf16x8*)(&Vs[0][swz0]) = stV0;
  *(bf16x8*)(&Vs[0][swz1]) = stV1;
  __syncthreads();

  for (int t2 = 0; t2 < 16; ++t2) {
#pragma unroll
    for (int half = 0; half < 2; ++half) {
      const int t = t2 * 2 + half;
      const int kv0 = t * 64;
      const bool last = (t == 31);

      // ---- issue next tile's global loads (hide under compute) ----
      if (!last) {
        const int sg = kv0 + 64;
        stK0 = *(const bf16x8*)(Kbase + (size_t)(sg + r0) * DD + sj * 8);
        stK1 = *(const bf16x8*)(Kbase + (size_t)(sg + r1) * DD + sj * 8);
        stV0 = *(const bf16x8*)(Vbase + (size_t)r0 * SS + sg + sj * 8);
        stV1 = *(const bf16x8*)(Vbase + (size_t)r1 * SS + sg + sj * 8);
      }

      // ---- QK^T: st[kvb] over 4 d-slices ----
      f32x16 st[2] = {};
#pragma unroll
      for (int kvb = 0; kvb < 2; ++kvb) {
        const int krow = kvb * 32 + l31;
        const int kro = krow * 64, kr7 = krow & 7;
#pragma unroll
        for (int ks = 0; ks < 4; ++ks) {
          bf16x8 ka = *(const bf16x8*)(&Ks[half][kro + (((2 * ks + hi) ^ kr7) * 8)]);
          st[kvb] = MFMA32(ka, qB[ks], st[kvb]);
        }
      }

      // ---- V^T frags (issue early; latency hides under softmax) ----
      bf16x8 va[2][4];
#pragma unroll
      for (int db = 0; db < 2; ++db) {
        const int vrow = db * 32 + l31;
        const int vro = vrow * 64, vr7 = vrow & 7;
#pragma unroll
        for (int sl = 0; sl < 4; ++sl)
          va[db][sl] = *(const bf16x8*)(&Vs[half][vro + (((2 * sl + hi) ^ vr7) * 8)]);
      }

      // ---- softmax: p = exp2(st*scale*log2e + mask*log2e), in place ----
#pragma unroll
      for (int kvb = 0; kvb < 2; ++kvb) {
#pragma unroll
        for (int rg = 0; rg < 4; ++rg) {
          f32x4 mk = *(const f32x4*)(mbase + kv0 + kvb * 32 + rg * 8 + hi4);
          mk *= LOG2E;
#pragma unroll
          for (int j = 0; j < 4; ++j) {
            float e = fast_exp2(fmaf(st[kvb][rg * 4 + j], SCALE_LOG2E, mk[j]));
            st[kvb][rg * 4 + j] = e;
            lacc[j] += e;
          }
        }
      }

      // ---- P repack (shfl_xor(32) + select) and PV MFMAs ----
#pragma unroll
      for (int kvb = 0; kvb < 2; ++kvb) {
#pragma unroll
        for (int s2 = 0; s2 < 2; ++s2) {
          unsigned L0 = pack2(st[kvb][8 * s2 + 0], st[kvb][8 * s2 + 1]);
          unsigned L1 = pack2(st[kvb][8 * s2 + 2], st[kvb][8 * s2 + 3]);
          unsigned H0 = pack2(st[kvb][8 * s2 + 4], st[kvb][8 * s2 + 5]);
          unsigned H1 = pack2(st[kvb][8 * s2 + 6], st[kvb][8 * s2 + 7]);
          unsigned xL0 = (unsigned)__shfl_xor((int)L0, 32);
          unsigned xL1 = (unsigned)__shfl_xor((int)L1, 32);
          unsigned xH0 = (unsigned)__shfl_xor((int)H0, 32);
          unsigned xH1 = (unsigned)__shfl_xor((int)H1, 32);
          union { unsigned u[4]; bf16x8 v; } pb;
          pb.u[0] = hi ? xH0 : L0;   // e0,e1: own L0 / partner H0
          pb.u[1] = hi ? xH1 : L1;   // e2,e3
          pb.u[2] = hi ? H0 : xL0;   // e4,e5: partner L0 / own H0
          pb.u[3] = hi ? H1 : xL1;   // e6,e7
          const int sl = kvb * 2 + s2;
          acc[0] = MFMA32(va[0][sl], pb.v, acc[0]);
          acc[1] = MFMA32(va[1][sl], pb.v, acc[1]);
        }
      }

      // ---- write next tile to other buffer, then barrier ----
      if (!last) {
        *(bf16x8*)(&Ks[half ^ 1][swz0]) = stK0;
        *(bf16x8*)(&Ks[half ^ 1][swz1]) = stK1;
        *(bf16x8*)(&Vs[half ^ 1][swz0]) = stV0;
        *(bf16x8*)(&Vs[half ^ 1][swz1]) = stV1;
      }
      __syncthreads();
    }
  }

  // ---- lsum: halves hold disjoint kv subsets; combine across hi ----
  float ls = lacc[0] + lacc[1] + lacc[2] + lacc[3];
  ls += __shfl_xor(ls, 32);
  const float inv = 1.0f / ls;

  // ---- store ctx[qg][d] = acc^T * inv;  d = 32db + 8rg + 4hi + j ----
  float* op = out + ((size_t)(b * SS + qg)) * DD + h * HD;
#pragma unroll
  for (int db = 0; db < 2; ++db)
#pragma unroll
    for (int rg = 0; rg < 4; ++rg) {
      f32x4 v;
#pragma unroll
      for (int j = 0; j < 4; ++j) v[j] = acc[db][rg * 4 + j] * inv;
      *(f32x4*)(op + db * 32 + rg * 8 + hi4) = v;
    }
}

// ---------------------------------------------------------------------------
extern "C" void kernel_launch(void* const* d_in, const int* in_sizes, int n_in,
                              void* d_out, int out_size, void* d_ws, size_t ws_size,
                              hipStream_t stream) {
  const float* X    = (const float*)d_in[0];
  const float* mask = (const float*)d_in[1];
  const float* Wq   = (const float*)d_in[2];
  const float* bq   = (const float*)d_in[3];
  const float* Wk   = (const float*)d_in[4];
  const float* bk   = (const float*)d_in[5];
  const float* Wv   = (const float*)d_in[6];
  const float* bv   = (const float*)d_in[7];

  bf16* Qw = (bf16*)d_ws;
  bf16* Kw = Qw + (size_t)BB * SS * DD;
  bf16* Vt = Kw + (size_t)BB * SS * DD;

  dim3 g1((BB * SS) / 128, DD / 128, 3);
  qkv_gemm<<<g1, 256, 0, stream>>>(X, Wq, bq, Wk, bk, Wv, bv, Qw, Kw, Vt);

  dim3 g2(BB * HH, SS / 128);  // 64 x 16
  attn<<<g2, 256, 0, stream>>>(Qw, Kw, Vt, mask, (float*)d_out);
}